// Round 14
// baseline (750.896 us; speedup 1.0000x reference)
//
#include <hip/hip_runtime.h>
#include <hip/hip_bf16.h>

#define NV 100000
#define EPSB 1e-5f

typedef unsigned short u16;
typedef unsigned int u32;
typedef _Float16 hv2 __attribute__((ext_vector_type(2)));
typedef _Float16 h8  __attribute__((ext_vector_type(8)));
typedef float f32x4  __attribute__((ext_vector_type(4)));

__device__ __forceinline__ u32 pkh(float x, float y) {
  auto h = __builtin_amdgcn_cvt_pkrtz(x, y);
  union { decltype(h) v; u32 u; } c; c.v = h; return c.u;
}
__device__ __forceinline__ float fdot2(u32 w, u32 x, float acc) {
#if __has_builtin(__builtin_amdgcn_fdot2)
  union { u32 u; hv2 h; } a, b; a.u = w; b.u = x;
  return __builtin_amdgcn_fdot2(a.h, b.h, acc, false);
#else
  union { u32 u; hv2 h; } a, b; a.u = w; b.u = x;
  return acc + (float)a.h.x*(float)b.h.x + (float)a.h.y*(float)b.h.y;
#endif
}
__device__ __forceinline__ u32 bcastu(u32 v, int l) {
  return (u32)__builtin_amdgcn_readlane((int)v, l);
}
__device__ __forceinline__ hv2 as_hv(u32 u) {
  union { u32 u; hv2 h; } c; c.u = u; return c.h;
}
__device__ __forceinline__ u32 as_u32h(hv2 h) {
  union { hv2 h; u32 u; } c; c.h = h; return c.u;
}
__device__ __forceinline__ hv2 hmax2v(hv2 a, hv2 b) {
#if __has_builtin(__builtin_elementwise_max)
  return __builtin_elementwise_max(a, b);
#else
  hv2 r; r.x = a.x > b.x ? a.x : b.x; r.y = a.y > b.y ? a.y : b.y; return r;
#endif
}
__device__ __forceinline__ hv2 hfma2v(hv2 a, hv2 b, hv2 c) {
#if __has_builtin(__builtin_elementwise_fma)
  return __builtin_elementwise_fma(a, b, c);
#else
  return a * b + c;
#endif
}
__device__ __forceinline__ u16 f2h(float x) { return (u16)(pkh(x, x) & 0xffffu); }
__device__ __forceinline__ float h2f(u16 u) {
  union { u16 u; _Float16 h; } c; c.u = u; return (float)c.h;
}
__device__ __forceinline__ f32x4 mfma16(h8 a, h8 b, f32x4 c) {
  return __builtin_amdgcn_mfma_f32_16x16x32_f16(a, b, c, 0, 0, 0);
}

// ---------------------------------------------------------------------------
// K0: detect key_mask element width (int32 vs byte-bool).
// ---------------------------------------------------------------------------
__global__ void k0_detect(const u32* __restrict__ km, int* __restrict__ flag) {
  int bad = 0;
  for (int i = threadIdx.x; i < 4096; i += 256) {
    u32 v = km[i];
    bad |= (v != 0u && v != 1u && v != 0x3F800000u) ? 1 : 0;
  }
  unsigned long long m = __ballot(bad != 0);
  __shared__ int sbad[4];
  if ((threadIdx.x & 63) == 0) sbad[threadIdx.x >> 6] = (m != 0ull);
  __syncthreads();
  if (threadIdx.x == 0) flag[0] = !(sbad[0] | sbad[1] | sbad[2] | sbad[3]);
}

// ---------------------------------------------------------------------------
// K_wpack: pack attention weights into global f16-pair tables (L1-resident
// in k1: 32KB total, fits the 32KB/CU L1).  Layouts identical to the former
// LDS arrays: Wg[0..1023]=WQP2, +1024=WKP2, +2048=WVP2, +3072=WOP2.
// ---------------------------------------------------------------------------
__global__ __launch_bounds__(512) void k_wpack(
    const float* __restrict__ wq, const float* __restrict__ wk,
    const float* __restrict__ wv, const float* __restrict__ wo,
    uint2* __restrict__ Wg)
{
  for (int e = threadIdx.x; e < 1024; e += 512) {
    int cp = e >> 6, i = e & 63;
    uint2 v;
    v.x = pkh(wq[i*64 + 2*cp],      wq[i*64 + 2*cp + 1]);
    v.y = pkh(wq[i*64 + 2*cp + 32], wq[i*64 + 2*cp + 33]);
    Wg[e] = v;
    int lo = (cp < 8) ? cp : cp + 8, hi = lo + 8;
    v.x = pkh(wk[2*lo*64 + i], wk[(2*lo+1)*64 + i]);
    v.y = pkh(wk[2*hi*64 + i], wk[(2*hi+1)*64 + i]);
    Wg[1024 + e] = v;
    v.x = pkh(wv[i*64 + 2*cp],      wv[i*64 + 2*cp + 1]);
    v.y = pkh(wv[i*64 + 2*cp + 32], wv[i*64 + 2*cp + 33]);
    Wg[2048 + e] = v;
    v.x = pkh(wo[i*64 + 2*cp],      wo[i*64 + 2*cp + 1]);
    v.y = pkh(wo[i*64 + 2*cp + 32], wo[i*64 + 2*cp + 33]);
    Wg[3072 + e] = v;
  }
}

// ---------------------------------------------------------------------------
// Kprep: VP[m][cp] = { pkh(vf pair), pkh(P pair) }  (frozen, round 8)
// ---------------------------------------------------------------------------
__global__ __launch_bounds__(256) void k_prep(
    const float* __restrict__ vf, const float* __restrict__ coords,
    const float* __restrict__ kpw, u32* __restrict__ VP)
{
  const int t = blockIdx.x*256 + threadIdx.x;
  const int cp = t & 31;
  const float wa0 = kpw[(2*cp)*3],   wa1 = kpw[(2*cp)*3+1],   wa2 = kpw[(2*cp)*3+2];
  const float wb0 = kpw[(2*cp+1)*3], wb1 = kpw[(2*cp+1)*3+1], wb2 = kpw[(2*cp+1)*3+2];
  for (int e = t; e < NV*32; e += 524288) {
    const int m = e >> 5;
    const float2 v2 = *(const float2*)&vf[(u32)m*64u + 2u*(u32)cp];
    const float c0 = coords[m*3], c1 = coords[m*3+1], c2 = coords[m*3+2];
    const float P0 = fmaf(wa0, c0, fmaf(wa1, c1, wa2*c2));
    const float P1 = fmaf(wb0, c0, fmaf(wb1, c1, wb2*c2));
    uint2 o; o.x = pkh(v2.x, v2.y); o.y = pkh(P0, P1);
    *(uint2*)&VP[(u32)e*2u] = o;
  }
}

// ---------------------------------------------------------------------------
// K1: gather attention.  Round-14: weights moved LDS -> global (L1-cached);
// per-block LDS 76 -> 43.5KB => 3 blocks/CU = 6 waves/SIMD (1.5x occupancy).
// Inner math bit-identical to round 12.  __launch_bounds__(512,6): VGPR<=85.
// ---------------------------------------------------------------------------
__global__ __launch_bounds__(512, 6) void k1_attn(
    const float* __restrict__ vf, const float* __restrict__ coords,
    const int* __restrict__ kidx, const void* __restrict__ kmaskv,
    const int* __restrict__ mflag, const u32* __restrict__ VP,
    const uint2* __restrict__ Wg,
    const float* __restrict__ bq, const float* __restrict__ bv,
    const float* __restrict__ bo,
    const float* __restrict__ qpw, const float* __restrict__ qpb,
    const float* __restrict__ kpb,
    float* __restrict__ x1pre, float* __restrict__ stats)
{
  extern __shared__ char smem[];
  const uint2* WQP2 = Wg;            // [cp 0..15][i]: {wq cp, wq cp+16}
  const uint2* WKP2 = Wg + 1024;     // [p 0..15][c]: p<8 {p,p+8} else {p+8,p+24}
  const uint2* WVP2 = Wg + 2048;
  const uint2* WOP2 = Wg + 3072;
  const int tid = threadIdx.x, wid = tid >> 6, lane = tid & 63;

  u32* wbase = (u32*)smem + wid * 1360;
  u32*   KFp  = wbase;                    // [32 keys][34] f16 c-pairs (pitch 34)
  uint2* QKH2 = (uint2*)(wbase + 1088);   // [hp][cp 0..31]: {head 2hp, 2hp+1}
  uint2* API2 = QKH2;                     // alias: attn pairs after scores
  u32*   SPP  = wbase + 1216;             // [4 heads][34]: interleave {cp, cp+16}

  const int cl = lane & 31, kh = lane >> 5, hp = lane >> 5, hh = lane >> 4;
  const int ca = 2*cl;
  const float qp0 = qpw[lane*3], qp1 = qpw[lane*3+1], qp2 = qpw[lane*3+2], qpbl = qpb[lane];
  const hv2 kpbp = as_hv(pkh(kpb[ca], kpb[ca+1]));
  const hv2 z2 = (hv2)(_Float16)0;
  const float bql = bq[lane], bvl = bv[lane], bol = bo[lane];
  const int mode4 = mflag[0];
  const u32* km32 = (const u32*)kmaskv;
  const unsigned char* km8 = (const unsigned char*)kmaskv;
  float ssum = 0.f, ssq = 0.f;

  for (int n = blockIdx.x*8 + wid; n < NV; n += 6144) {
    const float cn0 = coords[n*3], cn1 = coords[n*3+1], cn2 = coords[n*3+2];
    u32 mk;
    if (mode4) mk = (km32[n*32 + cl] != 0u);
    else       mk = (km8[n*32 + cl]  != 0u);
    const float vfl = vf[(u32)n*64u + (u32)lane];
    const uint2 wn = *(const uint2*)&VP[(u32)n*64u + (u32)ca];
    const hv2 pnp = as_hv(wn.y) - kpbp;

    union { int4 v[4]; int s[16]; } iu;
    {
      const int4* kp4 = (const int4*)(kidx + (u32)n*32u + (u32)(kh*16));
      iu.v[0] = kp4[0]; iu.v[1] = kp4[1]; iu.v[2] = kp4[2]; iu.v[3] = kp4[3];
    }

    // ---- issue all 16 gathers first (latency hides under q/qk compute) ----
    uint2 g[16];
    #pragma unroll
    for (int k = 0; k < 16; ++k) {
      const u32 off = ((u32)iu.s[k] << 6) + (u32)ca;
      g[k] = *(const uint2*)&VP[off];
    }

    // ---- gather-independent compute: query, q, qk (weights via L1) ----
    float query = vfl + fmaxf(fmaf(qp0,cn0,fmaf(qp1,cn1,fmaf(qp2,cn2,qpbl))), 0.f);
    const u32 qpk = pkh(query, __shfl_down(query, 1));

    float qa0 = bql, qa1 = 0.f;
    #pragma unroll
    for (int cp = 0; cp < 16; ++cp) {
      uint2 w = WQP2[cp*64 + lane];
      qa0 = fdot2(w.x, bcastu(qpk, 2*cp     ), qa0);
      qa1 = fdot2(w.y, bcastu(qpk, 2*cp + 32), qa1);
    }
    const float qacc = (qa0 + qa1) * 0.25f;
    const u32 qpk2 = pkh(qacc, __shfl_down(qacc, 1));

    float qkh0=0.f, qkh1=0.f, qkh2=0.f, qkh3=0.f;
    #pragma unroll
    for (int p = 0; p < 8; ++p) {
      uint2 wA = WKP2[ p    *64 + lane];
      uint2 wB = WKP2[(p+8) *64 + lane];
      qkh0 = fdot2(wA.x, bcastu(qpk2, 2*p     ), qkh0);
      qkh1 = fdot2(wA.y, bcastu(qpk2, 2*p + 16), qkh1);
      qkh2 = fdot2(wB.x, bcastu(qpk2, 2*p + 32), qkh2);
      qkh3 = fdot2(wB.y, bcastu(qpk2, 2*p + 48), qkh3);
    }
    {
      float t0 = __shfl_down(qkh0, 1), t1 = __shfl_down(qkh1, 1);
      float t2 = __shfl_down(qkh2, 1), t3 = __shfl_down(qkh3, 1);
      if ((lane & 1) == 0) {
        int j = lane >> 1;
        uint2 v0; v0.x = pkh(qkh0, t0); v0.y = pkh(qkh1, t1);
        uint2 v1; v1.x = pkh(qkh2, t2); v1.y = pkh(qkh3, t3);
        QKH2[j]      = v0;
        QKH2[32 + j] = v1;
      }
    }

    // ---- pack gathered keys -> KFp ----
    #pragma unroll
    for (int k = 0; k < 16; ++k) {
      hv2 pe = hmax2v(as_hv(g[k].y) - pnp, z2);
      KFp[(kh*16 + k)*34 + cl] = as_u32h(as_hv(g[k].x) + pe);
    }

    // ---- scores: lane -> key cl, heads (2hp, 2hp+1) ----
    float s00=0.f, s01=0.f, s10=0.f, s11=0.f;
    {
      const u32* kfrow = KFp + cl*34;
      const uint2* qrow = QKH2 + hp*32;
      #pragma unroll
      for (int c2 = 0; c2 < 16; ++c2) {
        uint2 kf = *(const uint2*)(kfrow + 2*c2);
        uint2 q0 = qrow[2*c2];
        uint2 q1 = qrow[2*c2 + 1];
        s00 = fdot2(kf.x, q0.x, s00);
        s10 = fdot2(kf.x, q0.y, s10);
        s01 = fdot2(kf.y, q1.x, s01);
        s11 = fdot2(kf.y, q1.y, s11);
      }
    }
    float sc0 = s00 + s01, sc1 = s10 + s11;
    if (mk) { sc0 = -1e30f; sc1 = -1e30f; }

    // ---- softmax over k within each 32-lane half ----
    float m0 = sc0, m1 = sc1;
    #pragma unroll
    for (int off = 16; off; off >>= 1) {
      m0 = fmaxf(m0, __shfl_xor(m0, off));
      m1 = fmaxf(m1, __shfl_xor(m1, off));
    }
    float p0 = __expf(sc0 - m0), p1 = __expf(sc1 - m1);
    float s0 = p0, s1 = p1;
    #pragma unroll
    for (int off = 16; off; off >>= 1) {
      s0 += __shfl_xor(s0, off);
      s1 += __shfl_xor(s1, off);
    }
    const float a0 = p0 / s0, a1 = p1 / s1;

    {
      uint2 ap; ap.x = pkh(a0, a0); ap.y = pkh(a1, a1);
      API2[lane] = ap;
    }

    // ---- PV: lane -> ch-pair j, heads (2hp,2hp+1) ----
    const int j = lane & 31;
    const int ab = hp << 5;
    hv2 accA = z2, accB = z2;
    #pragma unroll
    for (int k2 = 0; k2 < 32; ++k2) {
      hv2 kf = as_hv(KFp[k2*34 + j]);
      uint2 ap = API2[ab + k2];
      accA = hfma2v(kf, as_hv(ap.x), accA);
      accB = hfma2v(kf, as_hv(ap.y), accB);
    }
    {
      const int sj = (j & 15)*2 + (j >> 4);
      SPP[(2*hp  )*34 + sj] = as_u32h(accA);
      SPP[(2*hp+1)*34 + sj] = as_u32h(accB);
    }

    // ---- ctx[i] = Wv_h S[h] + bv (lane = i, h = i>>4) ----
    float ca0 = bvl, ca1 = 0.f;
    {
      const u32* sprow = SPP + hh*34;
      #pragma unroll
      for (int cp = 0; cp < 16; ++cp) {
        uint2 s = *(const uint2*)(sprow + 2*cp);
        uint2 w = WVP2[cp*64 + lane];
        ca0 = fdot2(w.x, s.x, ca0);
        ca1 = fdot2(w.y, s.y, ca1);
      }
    }
    const float cacc = ca0 + ca1;
    const u32 cpk = pkh(cacc, __shfl_down(cacc, 1));

    // ---- attend = Wo ctx + bo (lane = j) ----
    float oa0 = bol, oa1 = 0.f;
    #pragma unroll
    for (int cp = 0; cp < 16; ++cp) {
      uint2 w = WOP2[cp*64 + lane];
      oa0 = fdot2(w.x, bcastu(cpk, 2*cp     ), oa0);
      oa1 = fdot2(w.y, bcastu(cpk, 2*cp + 32), oa1);
    }
    const float aacc = oa0 + oa1;

    float x1 = vfl + aacc;
    x1pre[(u32)n*64u + (u32)lane] = x1;
    ssum += x1; ssq = fmaf(x1, x1, ssq);
  }

  // ---- block-reduce BN1 partials ----
  __syncthreads();
  float* red = (float*)smem;
  red[wid*64 + lane] = ssum;
  red[512 + wid*64 + lane] = ssq;
  __syncthreads();
  if (wid == 0) {
    float t1 = 0.f, t2 = 0.f;
    #pragma unroll
    for (int w = 0; w < 8; ++w) { t1 += red[w*64+lane]; t2 += red[512+w*64+lane]; }
    atomicAdd(&stats[lane], t1);
    atomicAdd(&stats[64+lane], t2);
  }
}

// ---------------------------------------------------------------------------
// K3 (MFMA): x2pre = x1 + FFN(BN1(x1pre)); BN2 partials.  (frozen, round 11)
// ---------------------------------------------------------------------------
__global__ __launch_bounds__(512) void k3_mfma(
    const float* __restrict__ x1pre, float* __restrict__ stats,
    const float* __restrict__ g1, const float* __restrict__ b1,
    const float* __restrict__ l1w, const float* __restrict__ l1b,
    const float* __restrict__ l2w, const float* __restrict__ l2b,
    float* __restrict__ x2pre)
{
  extern __shared__ char smem[];
  u32*   W1B  = (u32*)smem;
  u32*   W2B  = W1B + 8192;
  u16*   XA   = (u16*)(W2B + 8192);
  u16*   H    = XA + 4608;
  float* l1bs = (float*)(H + 16896);
  float* l2bs = l1bs + 256;
  float* scb  = l2bs + 64;
  float* shb  = scb + 64;
  float* red  = shb + 64;
  const int tid = threadIdx.x, wid = tid >> 6, lane = tid & 63;

  for (int e = tid; e < 8192; e += 512) {
    int j2 = e & 3, col = (e>>2) & 15, g = (e>>6) & 3, kk = (e>>8) & 1, n = e >> 9;
    int f = 16*n + col, k = kk*32 + g*8 + 2*j2;
    W1B[e] = pkh(l1w[f*64 + k], l1w[f*64 + k + 1]);
  }
  for (int e = tid; e < 8192; e += 512) {
    int j2 = e & 3, col = (e>>2) & 15, g = (e>>6) & 3, kk = (e>>8) & 7, n = e >> 11;
    int c = 16*n + col, k = kk*32 + g*8 + 2*j2;
    W2B[e] = pkh(l2w[c*256 + k], l2w[c*256 + k + 1]);
  }
  if (tid < 256) l1bs[tid] = l1b[tid];
  if (tid < 64)  l2bs[tid] = l2b[tid];
  if (tid < 64) {
    float mean = stats[tid] * (1.f/NV);
    float var  = stats[64+tid] * (1.f/NV) - mean*mean;
    float sc = rsqrtf(var + EPSB) * g1[tid];
    scb[tid] = sc;
    shb[tid] = b1[tid] - mean * sc;
  }
  if (tid < 128) red[tid] = 0.f;

  const int m  = wid & 3;
  const int wh = wid >> 2;
  const int lg = lane >> 4, ll = lane & 15;
  float ss0 = 0.f, sq0 = 0.f, ss1 = 0.f, sq1 = 0.f;

  for (int tile = blockIdx.x; tile < 1563; tile += 256) {
    const int base = tile * 64;
    __syncthreads();
    {
      int row = tid >> 3, cq = (tid & 7) * 8;
      int srow = base + row; if (srow >= NV) srow = NV - 1;
      const float* src = x1pre + (size_t)srow*64 + cq;
      u32* dst = (u32*)XA + row*36 + (tid & 7)*4;
      #pragma unroll
      for (int q = 0; q < 4; ++q) {
        float v0 = src[2*q]   * scb[cq+2*q]   + shb[cq+2*q];
        float v1 = src[2*q+1] * scb[cq+2*q+1] + shb[cq+2*q+1];
        dst[q] = pkh(v0, v1);
      }
    }
    __syncthreads();
    {
      const u16* arow = XA + (16*m + ll)*72 + lg*8;
      h8 a0 = *(const h8*)(arow);
      h8 a1 = *(const h8*)(arow + 32);
      #pragma unroll
      for (int nn = 0; nn < 8; ++nn) {
        int n = 8*wh + nn;
        const u32* bb = W1B + (n*8 + lg)*64 + ll*4;
        h8 b0 = *(const h8*)(bb);
        h8 b1v = *(const h8*)(bb + 256);
        f32x4 acc = {0.f, 0.f, 0.f, 0.f};
        acc = mfma16(a0, b0, acc);
        acc = mfma16(a1, b1v, acc);
        float bias = l1bs[16*n + ll];
        u16* hw = H + (16*m + lg*4)*264 + 16*n + ll;
        #pragma unroll
        for (int r = 0; r < 4; ++r)
          hw[r*264] = f2h(fmaxf(acc[r] + bias, 0.f));
      }
    }
    __syncthreads();
    {
      const u16* arow = H + (16*m + ll)*264 + lg*8;
      h8 a[8];
      #pragma unroll
      for (int kk = 0; kk < 8; ++kk) a[kk] = *(const h8*)(arow + kk*32);
      #pragma unroll
      for (int nn = 0; nn < 2; ++nn) {
        int n = 2*wh + nn;
        const u32* bb = W2B + (n*32 + lg)*64 + ll*4;
        f32x4 acA = {0.f,0.f,0.f,0.f}, acB = {0.f,0.f,0.f,0.f};
        #pragma unroll
        for (int kk = 0; kk < 8; kk += 2) {
          h8 b0 = *(const h8*)(bb + kk*256);
          h8 b1v = *(const h8*)(bb + (kk+1)*256);
          acA = mfma16(a[kk],   b0,  acA);
          acB = mfma16(a[kk+1], b1v, acB);
        }
        const int col = 16*n + ll;
        const float bias = l2bs[col];
        const u16* xr = XA + (16*m + lg*4)*72 + col;
        const int vox0 = base + 16*m + lg*4;
        float ss = 0.f, sq = 0.f;
        #pragma unroll
        for (int r = 0; r < 4; ++r) {
          int vox = vox0 + r;
          if (vox < NV) {
            float y = acA[r] + acB[r] + bias + h2f(xr[r*72]);
            x2pre[(size_t)vox*64 + col] = y;
            ss += y; sq = fmaf(y, y, sq);
          }
        }
        if (nn == 0) { ss0 += ss; sq0 += sq; } else { ss1 += ss; sq1 += sq; }
      }
    }
  }

  __syncthreads();
  const int c2a = 16*(2*wh)     + ll;
  const int c2b = 16*(2*wh + 1) + ll;
  atomicAdd(&red[c2a], ss0);
  atomicAdd(&red[64 + c2a], sq0);
  atomicAdd(&red[c2b], ss1);
  atomicAdd(&red[64 + c2b], sq1);
  __syncthreads();
  if (tid < 64) {
    atomicAdd(&stats[128+tid], red[tid]);
    atomicAdd(&stats[192+tid], red[64+tid]);
  }
}

// ---------------------------------------------------------------------------
// K4: x2 = BN2(x2pre); outpre = x2 @ out_w^T + out_b; BN3 partials. (frozen)
// ---------------------------------------------------------------------------
__global__ __launch_bounds__(256) void k4_out(
    const float* __restrict__ x2pre, float* __restrict__ stats,
    const float* __restrict__ g2, const float* __restrict__ b2,
    const float* __restrict__ outw, const float* __restrict__ outb,
    float* __restrict__ outpre)
{
  extern __shared__ char smem[];
  u32* WTP = (u32*)smem;
  const int tid = threadIdx.x, wid = tid >> 6, lane = tid & 63;
  for (int t = tid; t < 2048; t += 256) {
    int cp = t >> 6, o = t & 63;
    WTP[t] = pkh(outw[o*64 + 2*cp], outw[o*64 + 2*cp + 1]);
  }
  __syncthreads();

  const float mean = stats[128+lane] * (1.f/NV);
  const float var  = stats[192+lane] * (1.f/NV) - mean*mean;
  const float sc   = rsqrtf(var + EPSB) * g2[lane];
  const float sh   = b2[lane] - mean * sc;
  const float obl  = outb[lane];
  float ssum = 0.f, ssq = 0.f;

  const int stride = gridDim.x << 4;
  for (int n0 = blockIdx.x*16 + wid*4; n0 < NV; n0 += stride) {
    float xa = x2pre[(size_t) n0   *64+lane] * sc + sh;
    float xb = x2pre[(size_t)(n0+1)*64+lane] * sc + sh;
    float xc = x2pre[(size_t)(n0+2)*64+lane] * sc + sh;
    float xd = x2pre[(size_t)(n0+3)*64+lane] * sc + sh;
    const u32 xpa = pkh(xa, __shfl_down(xa,1));
    const u32 xpb = pkh(xb, __shfl_down(xb,1));
    const u32 xpc = pkh(xc, __shfl_down(xc,1));
    const u32 xpd = pkh(xd, __shfl_down(xd,1));
    float a0 = obl, a1 = obl, a2 = obl, a3 = obl;
    #pragma unroll 8
    for (int cp = 0; cp < 32; ++cp) {
      u32 w = WTP[cp*64 + lane];
      a0 = fdot2(w, bcastu(xpa, 2*cp), a0);
      a1 = fdot2(w, bcastu(xpb, 2*cp), a1);
      a2 = fdot2(w, bcastu(xpc, 2*cp), a2);
      a3 = fdot2(w, bcastu(xpd, 2*cp), a3);
    }
    outpre[(size_t) n0   *64+lane] = a0;
    outpre[(size_t)(n0+1)*64+lane] = a1;
    outpre[(size_t)(n0+2)*64+lane] = a2;
    outpre[(size_t)(n0+3)*64+lane] = a3;
    ssum += (a0 + a1) + (a2 + a3);
    ssq = fmaf(a0,a0, fmaf(a1,a1, fmaf(a2,a2, fmaf(a3,a3, ssq))));
  }

  __syncthreads();
  float* red = (float*)smem;
  red[wid*64+lane] = ssum;
  red[256 + wid*64 + lane] = ssq;
  __syncthreads();
  if (wid == 0) {
    float t1 = 0.f, t2 = 0.f;
    #pragma unroll
    for (int w = 0; w < 4; ++w) { t1 += red[w*64+lane]; t2 += red[256+w*64+lane]; }
    atomicAdd(&stats[256+lane], t1);
    atomicAdd(&stats[320+lane], t2);
  }
}

// ---------------------------------------------------------------------------
// K5: out = relu(BN3(outpre))  (frozen)
// ---------------------------------------------------------------------------
__global__ __launch_bounds__(256) void k5_fin(
    const float* __restrict__ outpre, const float* __restrict__ stats,
    const float* __restrict__ g3, const float* __restrict__ b3,
    float* __restrict__ out)
{
  const int t = blockIdx.x*256 + threadIdx.x;
  const int c0 = (t*4) & 63;
  float sc[4], sh[4];
  #pragma unroll
  for (int j = 0; j < 4; ++j) {
    int c = c0 + j;
    float mean = stats[256+c] * (1.f/NV);
    float var  = stats[320+c] * (1.f/NV) - mean*mean;
    sc[j] = rsqrtf(var + EPSB) * g3[c];
    sh[j] = b3[c] - mean*sc[j];
  }
  for (int i = t; i < NV*16; i += 131072) {
    float4 v = *(const float4*)&outpre[(size_t)i*4];
    v.x = fmaxf(fmaf(v.x, sc[0], sh[0]), 0.f);
    v.y = fmaxf(fmaf(v.y, sc[1], sh[1]), 0.f);
    v.z = fmaxf(fmaf(v.z, sc[2], sh[2]), 0.f);
    v.w = fmaxf(fmaf(v.w, sc[3], sh[3]), 0.f);
    *(float4*)&out[(size_t)i*4] = v;
  }
}

extern "C" void kernel_launch(void* const* d_in, const int* in_sizes, int n_in,
                              void* d_out, int out_size, void* d_ws, size_t ws_size,
                              hipStream_t stream) {
  (void)in_sizes; (void)n_in; (void)out_size; (void)ws_size;
  const float* vf     = (const float*)d_in[0];
  const float* coords = (const float*)d_in[1];
  const int*   kidx   = (const int*)d_in[2];
  const void*  kmask  = d_in[3];
  const float* wq  = (const float*)d_in[4];  const float* bq  = (const float*)d_in[5];
  const float* wk  = (const float*)d_in[6];  /* bk cancels in softmax */
  const float* wv  = (const float*)d_in[8];  const float* bv  = (const float*)d_in[9];
  const float* wo  = (const float*)d_in[10]; const float* bo  = (const float*)d_in[11];
  const float* qpw = (const float*)d_in[12]; const float* qpb = (const float*)d_in[13];
  const float* kpw = (const float*)d_in[14]; const float* kpb = (const float*)d_in[15];
  const float* g1  = (const float*)d_in[16]; const float* b1  = (const float*)d_in[17];
  const float* g2  = (const float*)d_in[18]; const float* b2  = (const float*)d_in[19];
  const float* l1w = (const float*)d_in[20]; const float* l1b = (const float*)d_in[21];
  const float* l2w = (const float*)d_in[22]; const float* l2b = (const float*)d_in[23];
  const float* outw= (const float*)d_in[24]; const float* outb= (const float*)d_in[25];
  const float* g3  = (const float*)d_in[26]; const float* b3  = (const float*)d_in[27];

  float* wsf    = (float*)d_ws;
  float* x1pre  = wsf;                       // [N*64]
  float* x2pre  = wsf + (size_t)NV*64;       // [N*64]; aliases VP before K3
  u32*   VP     = (u32*)x2pre;               // packed (vf,P) f16 table, dead after K1
  float* outpre = x1pre;                     // alias: x1pre dead after K3
  float* stats  = wsf + (size_t)2*NV*64;     // [384]
  int*   mflag  = (int*)(stats + 384);
  uint2* Wg     = (uint2*)(stats + 512);     // packed attn weights, 32KB

  (void)hipMemsetAsync(stats, 0, 384*sizeof(float), stream);

  (void)hipFuncSetAttribute((const void*)k1_attn, hipFuncAttributeMaxDynamicSharedMemorySize, 65536);
  (void)hipFuncSetAttribute((const void*)k3_mfma, hipFuncAttributeMaxDynamicSharedMemorySize, 110848);

  k0_detect<<<1, 256, 0, stream>>>((const u32*)kmask, mflag);
  k_wpack<<<1, 512, 0, stream>>>(wq, wk, wv, wo, Wg);
  k_prep<<<2048, 256, 0, stream>>>(vf, coords, kpw, VP);
  k1_attn<<<768, 512, 43520, stream>>>(vf, coords, kidx, kmask, mflag, VP,
      Wg, bq, bv, bo, qpw, qpb, kpb, x1pre, stats);
  k3_mfma<<<256, 512, 110848, stream>>>(x1pre, stats, g1, b1, l1w, l1b, l2w, l2b, x2pre);
  k4_out<<<1024, 256, 8192, stream>>>(x2pre, stats, g2, b2, outw, outb, outpre);
  k5_fin<<<512, 256, 0, stream>>>(outpre, stats, g3, b3, (float*)d_out);
}

// Round 15
// 297.667 us; speedup vs baseline: 2.5226x; 2.5226x over previous
//
#include <hip/hip_runtime.h>
#include <hip/hip_bf16.h>

#define NV 100000
#define EPSB 1e-5f

typedef unsigned short u16;
typedef unsigned int u32;
typedef _Float16 hv2 __attribute__((ext_vector_type(2)));
typedef _Float16 h8  __attribute__((ext_vector_type(8)));
typedef float f32x4  __attribute__((ext_vector_type(4)));

__device__ __forceinline__ u32 pkh(float x, float y) {
  auto h = __builtin_amdgcn_cvt_pkrtz(x, y);
  union { decltype(h) v; u32 u; } c; c.v = h; return c.u;
}
__device__ __forceinline__ float fdot2(u32 w, u32 x, float acc) {
#if __has_builtin(__builtin_amdgcn_fdot2)
  union { u32 u; hv2 h; } a, b; a.u = w; b.u = x;
  return __builtin_amdgcn_fdot2(a.h, b.h, acc, false);
#else
  union { u32 u; hv2 h; } a, b; a.u = w; b.u = x;
  return acc + (float)a.h.x*(float)b.h.x + (float)a.h.y*(float)b.h.y;
#endif
}
__device__ __forceinline__ u32 bcastu(u32 v, int l) {
  return (u32)__builtin_amdgcn_readlane((int)v, l);
}
__device__ __forceinline__ hv2 as_hv(u32 u) {
  union { u32 u; hv2 h; } c; c.u = u; return c.h;
}
__device__ __forceinline__ u32 as_u32h(hv2 h) {
  union { hv2 h; u32 u; } c; c.h = h; return c.u;
}
__device__ __forceinline__ hv2 hmax2v(hv2 a, hv2 b) {
#if __has_builtin(__builtin_elementwise_max)
  return __builtin_elementwise_max(a, b);
#else
  hv2 r; r.x = a.x > b.x ? a.x : b.x; r.y = a.y > b.y ? a.y : b.y; return r;
#endif
}
__device__ __forceinline__ hv2 hfma2v(hv2 a, hv2 b, hv2 c) {
#if __has_builtin(__builtin_elementwise_fma)
  return __builtin_elementwise_fma(a, b, c);
#else
  return a * b + c;
#endif
}
__device__ __forceinline__ u16 f2h(float x) { return (u16)(pkh(x, x) & 0xffffu); }
__device__ __forceinline__ float h2f(u16 u) {
  union { u16 u; _Float16 h; } c; c.u = u; return (float)c.h;
}
__device__ __forceinline__ f32x4 mfma16(h8 a, h8 b, f32x4 c) {
  return __builtin_amdgcn_mfma_f32_16x16x32_f16(a, b, c, 0, 0, 0);
}

// ---------------------------------------------------------------------------
// K0: detect key_mask element width (int32 vs byte-bool).
// ---------------------------------------------------------------------------
__global__ void k0_detect(const u32* __restrict__ km, int* __restrict__ flag) {
  int bad = 0;
  for (int i = threadIdx.x; i < 4096; i += 256) {
    u32 v = km[i];
    bad |= (v != 0u && v != 1u && v != 0x3F800000u) ? 1 : 0;
  }
  unsigned long long m = __ballot(bad != 0);
  __shared__ int sbad[4];
  if ((threadIdx.x & 63) == 0) sbad[threadIdx.x >> 6] = (m != 0ull);
  __syncthreads();
  if (threadIdx.x == 0) flag[0] = !(sbad[0] | sbad[1] | sbad[2] | sbad[3]);
}

// ---------------------------------------------------------------------------
// Kprep: VP[m][cp] = { pkh(vf pair), pkh(P pair) }  (frozen, round 8)
// ---------------------------------------------------------------------------
__global__ __launch_bounds__(256) void k_prep(
    const float* __restrict__ vf, const float* __restrict__ coords,
    const float* __restrict__ kpw, u32* __restrict__ VP)
{
  const int t = blockIdx.x*256 + threadIdx.x;
  const int cp = t & 31;
  const float wa0 = kpw[(2*cp)*3],   wa1 = kpw[(2*cp)*3+1],   wa2 = kpw[(2*cp)*3+2];
  const float wb0 = kpw[(2*cp+1)*3], wb1 = kpw[(2*cp+1)*3+1], wb2 = kpw[(2*cp+1)*3+2];
  for (int e = t; e < NV*32; e += 524288) {
    const int m = e >> 5;
    const float2 v2 = *(const float2*)&vf[(u32)m*64u + 2u*(u32)cp];
    const float c0 = coords[m*3], c1 = coords[m*3+1], c2 = coords[m*3+2];
    const float P0 = fmaf(wa0, c0, fmaf(wa1, c1, wa2*c2));
    const float P1 = fmaf(wb0, c0, fmaf(wb1, c1, wb2*c2));
    uint2 o; o.x = pkh(v2.x, v2.y); o.y = pkh(P0, P1);
    *(uint2*)&VP[(u32)e*2u] = o;
  }
}

// ---------------------------------------------------------------------------
// K1: gather attention.  Round-15 = round-13 config (weights in LDS,
// 512 blocks x 512 thr, 2 blocks/CU) + 2-deep gather pipeline: voxel i+1's
// 16 VP gathers are issued during iteration i (right after packing voxel
// i's), giving them a full iteration (>>900cy) to land.  Math bit-identical.
// ---------------------------------------------------------------------------
__global__ __launch_bounds__(512, 4) void k1_attn(
    const float* __restrict__ vf, const float* __restrict__ coords,
    const int* __restrict__ kidx, const void* __restrict__ kmaskv,
    const int* __restrict__ mflag, const u32* __restrict__ VP,
    const float* __restrict__ wq, const float* __restrict__ bq,
    const float* __restrict__ wk,
    const float* __restrict__ wv, const float* __restrict__ bv,
    const float* __restrict__ wo, const float* __restrict__ bo,
    const float* __restrict__ qpw, const float* __restrict__ qpb,
    const float* __restrict__ kpb,
    float* __restrict__ x1pre, float* __restrict__ stats)
{
  extern __shared__ char smem[];
  uint2* WQP2 = (uint2*)smem;        // [cp 0..15][i]: {wq cp, wq cp+16} 8KB
  uint2* WKP2 = WQP2 + 1024;         // [p 0..15][c]: p<8 {p,p+8} else {p+8,p+24}
  uint2* WVP2 = WKP2 + 1024;
  uint2* WOP2 = WVP2 + 1024;
  const int tid = threadIdx.x, wid = tid >> 6, lane = tid & 63;

  for (int t = tid; t < 1024; t += 512) {
    int cp = t >> 6, i = t & 63;
    uint2 v;
    v.x = pkh(wq[i*64 + 2*cp],      wq[i*64 + 2*cp + 1]);
    v.y = pkh(wq[i*64 + 2*cp + 32], wq[i*64 + 2*cp + 33]);
    WQP2[t] = v;
    int lo = (cp < 8) ? cp : cp + 8, hi = lo + 8;
    v.x = pkh(wk[2*lo*64 + i], wk[(2*lo+1)*64 + i]);
    v.y = pkh(wk[2*hi*64 + i], wk[(2*hi+1)*64 + i]);
    WKP2[t] = v;
    v.x = pkh(wv[i*64 + 2*cp],      wv[i*64 + 2*cp + 1]);
    v.y = pkh(wv[i*64 + 2*cp + 32], wv[i*64 + 2*cp + 33]);
    WVP2[t] = v;
    v.x = pkh(wo[i*64 + 2*cp],      wo[i*64 + 2*cp + 1]);
    v.y = pkh(wo[i*64 + 2*cp + 32], wo[i*64 + 2*cp + 33]);
    WOP2[t] = v;
  }
  __syncthreads();

  u32* wbase = (u32*)(smem + 32768) + wid * 1360;
  u32*   KFp  = wbase;                    // [32 keys][34] f16 c-pairs (pitch 34)
  uint2* QKH2 = (uint2*)(wbase + 1088);   // [hp][cp 0..31]: {head 2hp, 2hp+1}
  uint2* API2 = QKH2;                     // alias: attn pairs after scores
  u32*   SPP  = wbase + 1216;             // [4 heads][34]: interleave {cp, cp+16}

  const int cl = lane & 31, kh = lane >> 5, hp = lane >> 5, hh = lane >> 4;
  const int ca = 2*cl;
  const float qp0 = qpw[lane*3], qp1 = qpw[lane*3+1], qp2 = qpw[lane*3+2], qpbl = qpb[lane];
  const hv2 kpbp = as_hv(pkh(kpb[ca], kpb[ca+1]));
  const hv2 z2 = (hv2)(_Float16)0;
  const float bql = bq[lane], bvl = bv[lane], bol = bo[lane];
  const int mode4 = mflag[0];
  const u32* km32 = (const u32*)kmaskv;
  const unsigned char* km8 = (const unsigned char*)kmaskv;
  float ssum = 0.f, ssq = 0.f;

  union iu_t { int4 v[4]; int s[16]; };

  const int n0 = blockIdx.x*8 + wid;
  // ---- prologue: voxel n0's indices, scalars, AND gathers ----
  iu_t iu;
  float cn0 = 0.f, cn1 = 0.f, cn2 = 0.f, vfl = 0.f;
  uint2 wn = {0u, 0u};
  u32 mkraw = 0u;
  uint2 g[16];
  if (n0 < NV) {
    const int4* kp4 = (const int4*)(kidx + (u32)n0*32u + (u32)(kh*16));
    iu.v[0] = kp4[0]; iu.v[1] = kp4[1]; iu.v[2] = kp4[2]; iu.v[3] = kp4[3];
    cn0 = coords[n0*3]; cn1 = coords[n0*3+1]; cn2 = coords[n0*3+2];
    vfl = vf[(u32)n0*64u + (u32)lane];
    wn  = *(const uint2*)&VP[(u32)n0*64u + (u32)ca];
    mkraw = mode4 ? km32[n0*32 + cl] : (u32)km8[n0*32 + cl];
    #pragma unroll
    for (int k = 0; k < 16; ++k) {
      const u32 off = ((u32)iu.s[k] << 6) + (u32)ca;
      g[k] = *(const uint2*)&VP[off];
    }
  }

  for (int n = n0; n < NV; n += 4096) {
    // ---- prefetch next voxel's indices + scalars ----
    const int nn2 = n + 4096;
    const int np = (nn2 < NV) ? nn2 : n;     // clamped dummy on tail
    iu_t iun;
    {
      const int4* kp4 = (const int4*)(kidx + (u32)np*32u + (u32)(kh*16));
      iun.v[0] = kp4[0]; iun.v[1] = kp4[1]; iun.v[2] = kp4[2]; iun.v[3] = kp4[3];
    }
    const float cn0n = coords[np*3], cn1n = coords[np*3+1], cn2n = coords[np*3+2];
    const float vfln = vf[(u32)np*64u + (u32)lane];
    const uint2 wnn  = *(const uint2*)&VP[(u32)np*64u + (u32)ca];
    const u32 mkrawn = mode4 ? km32[np*32 + cl] : (u32)km8[np*32 + cl];

    const hv2 pnp = as_hv(wn.y) - kpbp;
    const u32 mk = (mkraw != 0u);

    // ---- gather-independent compute: query, q, qk ----
    float query = vfl + fmaxf(fmaf(qp0,cn0,fmaf(qp1,cn1,fmaf(qp2,cn2,qpbl))), 0.f);
    const u32 qpk = pkh(query, __shfl_down(query, 1));

    float qa0 = bql, qa1 = 0.f;
    #pragma unroll
    for (int cp = 0; cp < 16; ++cp) {
      uint2 w = WQP2[cp*64 + lane];
      qa0 = fdot2(w.x, bcastu(qpk, 2*cp     ), qa0);
      qa1 = fdot2(w.y, bcastu(qpk, 2*cp + 32), qa1);
    }
    const float qacc = (qa0 + qa1) * 0.25f;
    const u32 qpk2 = pkh(qacc, __shfl_down(qacc, 1));

    float qkh0=0.f, qkh1=0.f, qkh2=0.f, qkh3=0.f;
    #pragma unroll
    for (int p = 0; p < 8; ++p) {
      uint2 wA = WKP2[ p    *64 + lane];
      uint2 wB = WKP2[(p+8) *64 + lane];
      qkh0 = fdot2(wA.x, bcastu(qpk2, 2*p     ), qkh0);
      qkh1 = fdot2(wA.y, bcastu(qpk2, 2*p + 16), qkh1);
      qkh2 = fdot2(wB.x, bcastu(qpk2, 2*p + 32), qkh2);
      qkh3 = fdot2(wB.y, bcastu(qpk2, 2*p + 48), qkh3);
    }
    {
      float t0 = __shfl_down(qkh0, 1), t1 = __shfl_down(qkh1, 1);
      float t2 = __shfl_down(qkh2, 1), t3 = __shfl_down(qkh3, 1);
      if ((lane & 1) == 0) {
        int j = lane >> 1;
        uint2 v0; v0.x = pkh(qkh0, t0); v0.y = pkh(qkh1, t1);
        uint2 v1; v1.x = pkh(qkh2, t2); v1.y = pkh(qkh3, t3);
        QKH2[j]      = v0;
        QKH2[32 + j] = v1;
      }
    }

    // ---- pack gathered keys -> KFp (g issued a FULL iteration ago) ----
    #pragma unroll
    for (int k = 0; k < 16; ++k) {
      hv2 pe = hmax2v(as_hv(g[k].y) - pnp, z2);
      KFp[(kh*16 + k)*34 + cl] = as_u32h(as_hv(g[k].x) + pe);
    }

    // ---- issue NEXT voxel's gathers now (in flight across the rest of
    //      this iteration + next iteration's q/qk stretch) ----
    #pragma unroll
    for (int k = 0; k < 16; ++k) {
      const u32 off = ((u32)iun.s[k] << 6) + (u32)ca;
      g[k] = *(const uint2*)&VP[off];
    }

    // ---- scores: lane -> key cl, heads (2hp, 2hp+1) ----
    float s00=0.f, s01=0.f, s10=0.f, s11=0.f;
    {
      const u32* kfrow = KFp + cl*34;
      const uint2* qrow = QKH2 + hp*32;
      #pragma unroll
      for (int c2 = 0; c2 < 16; ++c2) {
        uint2 kf = *(const uint2*)(kfrow + 2*c2);
        uint2 q0 = qrow[2*c2];
        uint2 q1 = qrow[2*c2 + 1];
        s00 = fdot2(kf.x, q0.x, s00);
        s10 = fdot2(kf.x, q0.y, s10);
        s01 = fdot2(kf.y, q1.x, s01);
        s11 = fdot2(kf.y, q1.y, s11);
      }
    }
    float sc0 = s00 + s01, sc1 = s10 + s11;
    if (mk) { sc0 = -1e30f; sc1 = -1e30f; }

    // ---- softmax over k within each 32-lane half ----
    float m0 = sc0, m1 = sc1;
    #pragma unroll
    for (int off = 16; off; off >>= 1) {
      m0 = fmaxf(m0, __shfl_xor(m0, off));
      m1 = fmaxf(m1, __shfl_xor(m1, off));
    }
    float p0 = __expf(sc0 - m0), p1 = __expf(sc1 - m1);
    float s0 = p0, s1 = p1;
    #pragma unroll
    for (int off = 16; off; off >>= 1) {
      s0 += __shfl_xor(s0, off);
      s1 += __shfl_xor(s1, off);
    }
    const float a0 = p0 / s0, a1 = p1 / s1;

    {
      uint2 ap; ap.x = pkh(a0, a0); ap.y = pkh(a1, a1);
      API2[lane] = ap;
    }

    // ---- PV: lane -> ch-pair j, heads (2hp,2hp+1) ----
    const int j = lane & 31;
    const int ab = hp << 5;
    hv2 accA = z2, accB = z2;
    #pragma unroll
    for (int k2 = 0; k2 < 32; ++k2) {
      hv2 kf = as_hv(KFp[k2*34 + j]);
      uint2 ap = API2[ab + k2];
      accA = hfma2v(kf, as_hv(ap.x), accA);
      accB = hfma2v(kf, as_hv(ap.y), accB);
    }
    {
      const int sj = (j & 15)*2 + (j >> 4);
      SPP[(2*hp  )*34 + sj] = as_u32h(accA);
      SPP[(2*hp+1)*34 + sj] = as_u32h(accB);
    }

    // ---- ctx[i] = Wv_h S[h] + bv (lane = i, h = i>>4) ----
    float ca0 = bvl, ca1 = 0.f;
    {
      const u32* sprow = SPP + hh*34;
      #pragma unroll
      for (int cp = 0; cp < 16; ++cp) {
        uint2 s = *(const uint2*)(sprow + 2*cp);
        uint2 w = WVP2[cp*64 + lane];
        ca0 = fdot2(w.x, s.x, ca0);
        ca1 = fdot2(w.y, s.y, ca1);
      }
    }
    const float cacc = ca0 + ca1;
    const u32 cpk = pkh(cacc, __shfl_down(cacc, 1));

    // ---- attend = Wo ctx + bo (lane = j) ----
    float oa0 = bol, oa1 = 0.f;
    #pragma unroll
    for (int cp = 0; cp < 16; ++cp) {
      uint2 w = WOP2[cp*64 + lane];
      oa0 = fdot2(w.x, bcastu(cpk, 2*cp     ), oa0);
      oa1 = fdot2(w.y, bcastu(cpk, 2*cp + 32), oa1);
    }
    const float aacc = oa0 + oa1;

    float x1 = vfl + aacc;
    x1pre[(u32)n*64u + (u32)lane] = x1;
    ssum += x1; ssq = fmaf(x1, x1, ssq);

    // ---- rotate prefetched state ----
    iu = iun;
    cn0 = cn0n; cn1 = cn1n; cn2 = cn2n;
    vfl = vfln; wn = wnn; mkraw = mkrawn;
  }

  // ---- block-reduce BN1 partials ----
  __syncthreads();
  float* red = (float*)smem;
  red[wid*64 + lane] = ssum;
  red[512 + wid*64 + lane] = ssq;
  __syncthreads();
  if (wid == 0) {
    float t1 = 0.f, t2 = 0.f;
    #pragma unroll
    for (int w = 0; w < 8; ++w) { t1 += red[w*64+lane]; t2 += red[512+w*64+lane]; }
    atomicAdd(&stats[lane], t1);
    atomicAdd(&stats[64+lane], t2);
  }
}

// ---------------------------------------------------------------------------
// K3 (MFMA): x2pre = x1 + FFN(BN1(x1pre)); BN2 partials.  (frozen, round 11)
// ---------------------------------------------------------------------------
__global__ __launch_bounds__(512) void k3_mfma(
    const float* __restrict__ x1pre, float* __restrict__ stats,
    const float* __restrict__ g1, const float* __restrict__ b1,
    const float* __restrict__ l1w, const float* __restrict__ l1b,
    const float* __restrict__ l2w, const float* __restrict__ l2b,
    float* __restrict__ x2pre)
{
  extern __shared__ char smem[];
  u32*   W1B  = (u32*)smem;
  u32*   W2B  = W1B + 8192;
  u16*   XA   = (u16*)(W2B + 8192);
  u16*   H    = XA + 4608;
  float* l1bs = (float*)(H + 16896);
  float* l2bs = l1bs + 256;
  float* scb  = l2bs + 64;
  float* shb  = scb + 64;
  float* red  = shb + 64;
  const int tid = threadIdx.x, wid = tid >> 6, lane = tid & 63;

  for (int e = tid; e < 8192; e += 512) {
    int j2 = e & 3, col = (e>>2) & 15, g = (e>>6) & 3, kk = (e>>8) & 1, n = e >> 9;
    int f = 16*n + col, k = kk*32 + g*8 + 2*j2;
    W1B[e] = pkh(l1w[f*64 + k], l1w[f*64 + k + 1]);
  }
  for (int e = tid; e < 8192; e += 512) {
    int j2 = e & 3, col = (e>>2) & 15, g = (e>>6) & 3, kk = (e>>8) & 7, n = e >> 11;
    int c = 16*n + col, k = kk*32 + g*8 + 2*j2;
    W2B[e] = pkh(l2w[c*256 + k], l2w[c*256 + k + 1]);
  }
  if (tid < 256) l1bs[tid] = l1b[tid];
  if (tid < 64)  l2bs[tid] = l2b[tid];
  if (tid < 64) {
    float mean = stats[tid] * (1.f/NV);
    float var  = stats[64+tid] * (1.f/NV) - mean*mean;
    float sc = rsqrtf(var + EPSB) * g1[tid];
    scb[tid] = sc;
    shb[tid] = b1[tid] - mean * sc;
  }
  if (tid < 128) red[tid] = 0.f;

  const int m  = wid & 3;
  const int wh = wid >> 2;
  const int lg = lane >> 4, ll = lane & 15;
  float ss0 = 0.f, sq0 = 0.f, ss1 = 0.f, sq1 = 0.f;

  for (int tile = blockIdx.x; tile < 1563; tile += 256) {
    const int base = tile * 64;
    __syncthreads();
    {
      int row = tid >> 3, cq = (tid & 7) * 8;
      int srow = base + row; if (srow >= NV) srow = NV - 1;
      const float* src = x1pre + (size_t)srow*64 + cq;
      u32* dst = (u32*)XA + row*36 + (tid & 7)*4;
      #pragma unroll
      for (int q = 0; q < 4; ++q) {
        float v0 = src[2*q]   * scb[cq+2*q]   + shb[cq+2*q];
        float v1 = src[2*q+1] * scb[cq+2*q+1] + shb[cq+2*q+1];
        dst[q] = pkh(v0, v1);
      }
    }
    __syncthreads();
    {
      const u16* arow = XA + (16*m + ll)*72 + lg*8;
      h8 a0 = *(const h8*)(arow);
      h8 a1 = *(const h8*)(arow + 32);
      #pragma unroll
      for (int nn = 0; nn < 8; ++nn) {
        int n = 8*wh + nn;
        const u32* bb = W1B + (n*8 + lg)*64 + ll*4;
        h8 b0 = *(const h8*)(bb);
        h8 b1v = *(const h8*)(bb + 256);
        f32x4 acc = {0.f, 0.f, 0.f, 0.f};
        acc = mfma16(a0, b0, acc);
        acc = mfma16(a1, b1v, acc);
        float bias = l1bs[16*n + ll];
        u16* hw = H + (16*m + lg*4)*264 + 16*n + ll;
        #pragma unroll
        for (int r = 0; r < 4; ++r)
          hw[r*264] = f2h(fmaxf(acc[r] + bias, 0.f));
      }
    }
    __syncthreads();
    {
      const u16* arow = H + (16*m + ll)*264 + lg*8;
      h8 a[8];
      #pragma unroll
      for (int kk = 0; kk < 8; ++kk) a[kk] = *(const h8*)(arow + kk*32);
      #pragma unroll
      for (int nn = 0; nn < 2; ++nn) {
        int n = 2*wh + nn;
        const u32* bb = W2B + (n*32 + lg)*64 + ll*4;
        f32x4 acA = {0.f,0.f,0.f,0.f}, acB = {0.f,0.f,0.f,0.f};
        #pragma unroll
        for (int kk = 0; kk < 8; kk += 2) {
          h8 b0 = *(const h8*)(bb + kk*256);
          h8 b1v = *(const h8*)(bb + (kk+1)*256);
          acA = mfma16(a[kk],   b0,  acA);
          acB = mfma16(a[kk+1], b1v, acB);
        }
        const int col = 16*n + ll;
        const float bias = l2bs[col];
        const u16* xr = XA + (16*m + lg*4)*72 + col;
        const int vox0 = base + 16*m + lg*4;
        float ss = 0.f, sq = 0.f;
        #pragma unroll
        for (int r = 0; r < 4; ++r) {
          int vox = vox0 + r;
          if (vox < NV) {
            float y = acA[r] + acB[r] + bias + h2f(xr[r*72]);
            x2pre[(size_t)vox*64 + col] = y;
            ss += y; sq = fmaf(y, y, sq);
          }
        }
        if (nn == 0) { ss0 += ss; sq0 += sq; } else { ss1 += ss; sq1 += sq; }
      }
    }
  }

  __syncthreads();
  const int c2a = 16*(2*wh)     + ll;
  const int c2b = 16*(2*wh + 1) + ll;
  atomicAdd(&red[c2a], ss0);
  atomicAdd(&red[64 + c2a], sq0);
  atomicAdd(&red[c2b], ss1);
  atomicAdd(&red[64 + c2b], sq1);
  __syncthreads();
  if (tid < 64) {
    atomicAdd(&stats[128+tid], red[tid]);
    atomicAdd(&stats[192+tid], red[64+tid]);
  }
}

// ---------------------------------------------------------------------------
// K4: x2 = BN2(x2pre); outpre = x2 @ out_w^T + out_b; BN3 partials. (frozen)
// ---------------------------------------------------------------------------
__global__ __launch_bounds__(256) void k4_out(
    const float* __restrict__ x2pre, float* __restrict__ stats,
    const float* __restrict__ g2, const float* __restrict__ b2,
    const float* __restrict__ outw, const float* __restrict__ outb,
    float* __restrict__ outpre)
{
  extern __shared__ char smem[];
  u32* WTP = (u32*)smem;
  const int tid = threadIdx.x, wid = tid >> 6, lane = tid & 63;
  for (int t = tid; t < 2048; t += 256) {
    int cp = t >> 6, o = t & 63;
    WTP[t] = pkh(outw[o*64 + 2*cp], outw[o*64 + 2*cp + 1]);
  }
  __syncthreads();

  const float mean = stats[128+lane] * (1.f/NV);
  const float var  = stats[192+lane] * (1.f/NV) - mean*mean;
  const float sc   = rsqrtf(var + EPSB) * g2[lane];
  const float sh   = b2[lane] - mean * sc;
  const float obl  = outb[lane];
  float ssum = 0.f, ssq = 0.f;

  const int stride = gridDim.x << 4;
  for (int n0 = blockIdx.x*16 + wid*4; n0 < NV; n0 += stride) {
    float xa = x2pre[(size_t) n0   *64+lane] * sc + sh;
    float xb = x2pre[(size_t)(n0+1)*64+lane] * sc + sh;
    float xc = x2pre[(size_t)(n0+2)*64+lane] * sc + sh;
    float xd = x2pre[(size_t)(n0+3)*64+lane] * sc + sh;
    const u32 xpa = pkh(xa, __shfl_down(xa,1));
    const u32 xpb = pkh(xb, __shfl_down(xb,1));
    const u32 xpc = pkh(xc, __shfl_down(xc,1));
    const u32 xpd = pkh(xd, __shfl_down(xd,1));
    float a0 = obl, a1 = obl, a2 = obl, a3 = obl;
    #pragma unroll 8
    for (int cp = 0; cp < 32; ++cp) {
      u32 w = WTP[cp*64 + lane];
      a0 = fdot2(w, bcastu(xpa, 2*cp), a0);
      a1 = fdot2(w, bcastu(xpb, 2*cp), a1);
      a2 = fdot2(w, bcastu(xpc, 2*cp), a2);
      a3 = fdot2(w, bcastu(xpd, 2*cp), a3);
    }
    outpre[(size_t) n0   *64+lane] = a0;
    outpre[(size_t)(n0+1)*64+lane] = a1;
    outpre[(size_t)(n0+2)*64+lane] = a2;
    outpre[(size_t)(n0+3)*64+lane] = a3;
    ssum += (a0 + a1) + (a2 + a3);
    ssq = fmaf(a0,a0, fmaf(a1,a1, fmaf(a2,a2, fmaf(a3,a3, ssq))));
  }

  __syncthreads();
  float* red = (float*)smem;
  red[wid*64+lane] = ssum;
  red[256 + wid*64 + lane] = ssq;
  __syncthreads();
  if (wid == 0) {
    float t1 = 0.f, t2 = 0.f;
    #pragma unroll
    for (int w = 0; w < 4; ++w) { t1 += red[w*64+lane]; t2 += red[256+w*64+lane]; }
    atomicAdd(&stats[256+lane], t1);
    atomicAdd(&stats[320+lane], t2);
  }
}

// ---------------------------------------------------------------------------
// K5: out = relu(BN3(outpre))  (frozen)
// ---------------------------------------------------------------------------
__global__ __launch_bounds__(256) void k5_fin(
    const float* __restrict__ outpre, const float* __restrict__ stats,
    const float* __restrict__ g3, const float* __restrict__ b3,
    float* __restrict__ out)
{
  const int t = blockIdx.x*256 + threadIdx.x;
  const int c0 = (t*4) & 63;
  float sc[4], sh[4];
  #pragma unroll
  for (int j = 0; j < 4; ++j) {
    int c = c0 + j;
    float mean = stats[256+c] * (1.f/NV);
    float var  = stats[320+c] * (1.f/NV) - mean*mean;
    sc[j] = rsqrtf(var + EPSB) * g3[c];
    sh[j] = b3[c] - mean*sc[j];
  }
  for (int i = t; i < NV*16; i += 131072) {
    float4 v = *(const float4*)&outpre[(size_t)i*4];
    v.x = fmaxf(fmaf(v.x, sc[0], sh[0]), 0.f);
    v.y = fmaxf(fmaf(v.y, sc[1], sh[1]), 0.f);
    v.z = fmaxf(fmaf(v.z, sc[2], sh[2]), 0.f);
    v.w = fmaxf(fmaf(v.w, sc[3], sh[3]), 0.f);
    *(float4*)&out[(size_t)i*4] = v;
  }
}

extern "C" void kernel_launch(void* const* d_in, const int* in_sizes, int n_in,
                              void* d_out, int out_size, void* d_ws, size_t ws_size,
                              hipStream_t stream) {
  (void)in_sizes; (void)n_in; (void)out_size; (void)ws_size;
  const float* vf     = (const float*)d_in[0];
  const float* coords = (const float*)d_in[1];
  const int*   kidx   = (const int*)d_in[2];
  const void*  kmask  = d_in[3];
  const float* wq  = (const float*)d_in[4];  const float* bq  = (const float*)d_in[5];
  const float* wk  = (const float*)d_in[6];  /* bk cancels in softmax */
  const float* wv  = (const float*)d_in[8];  const float* bv  = (const float*)d_in[9];
  const float* wo  = (const float*)d_in[10]; const float* bo  = (const float*)d_in[11];
  const float* qpw = (const float*)d_in[12]; const float* qpb = (const float*)d_in[13];
  const float* kpw = (const float*)d_in[14]; const float* kpb = (const float*)d_in[15];
  const float* g1  = (const float*)d_in[16]; const float* b1  = (const float*)d_in[17];
  const float* g2  = (const float*)d_in[18]; const float* b2  = (const float*)d_in[19];
  const float* l1w = (const float*)d_in[20]; const float* l1b = (const float*)d_in[21];
  const float* l2w = (const float*)d_in[22]; const float* l2b = (const float*)d_in[23];
  const float* outw= (const float*)d_in[24]; const float* outb= (const float*)d_in[25];
  const float* g3  = (const float*)d_in[26]; const float* b3  = (const float*)d_in[27];

  float* wsf    = (float*)d_ws;
  float* x1pre  = wsf;                       // [N*64]
  float* x2pre  = wsf + (size_t)NV*64;       // [N*64]; aliases VP before K3
  u32*   VP     = (u32*)x2pre;               // packed (vf,P) f16 table, dead after K1
  float* outpre = x1pre;                     // alias: x1pre dead after K3
  float* stats  = wsf + (size_t)2*NV*64;     // [384]
  int*   mflag  = (int*)(stats + 384);

  (void)hipMemsetAsync(stats, 0, 384*sizeof(float), stream);

  (void)hipFuncSetAttribute((const void*)k1_attn, hipFuncAttributeMaxDynamicSharedMemorySize, 76288);
  (void)hipFuncSetAttribute((const void*)k3_mfma, hipFuncAttributeMaxDynamicSharedMemorySize, 110848);

  k0_detect<<<1, 256, 0, stream>>>((const u32*)kmask, mflag);
  k_prep<<<2048, 256, 0, stream>>>(vf, coords, kpw, VP);
  k1_attn<<<512, 512, 76288, stream>>>(vf, coords, kidx, kmask, mflag, VP,
      wq, bq, wk, wv, bv, wo, bo, qpw, qpb, kpb, x1pre, stats);
  k3_mfma<<<256, 512, 110848, stream>>>(x1pre, stats, g1, b1, l1w, l1b, l2w, l2b, x2pre);
  k4_out<<<1024, 256, 8192, stream>>>(x2pre, stats, g2, b2, outw, outb, outpre);
  k5_fin<<<512, 256, 0, stream>>>(outpre, stats, g3, b3, (float*)d_out);
}